// Round 5
// baseline (215.462 us; speedup 1.0000x reference)
//
#include <hip/hip_runtime.h>

// Problem constants (fixed by reference)
#define B_ 16
#define C_ 64
#define T_ 2048
#define O_ 64
#define KNN 3
#define HSPLIT 4
#define JCH (T_ / HSPLIT)     // 512 j per block

typedef short short8   __attribute__((ext_vector_type(8)));   // 8 bf16
typedef float f32x4    __attribute__((ext_vector_type(4)));
typedef unsigned short ushortx4 __attribute__((ext_vector_type(4)));

// Workspace layout (float slots). Total = 5,287,936 floats = 21.2 MB (== R4 footprint, proven).
#define XT_OFF 0                              // fp32 xT[b][t][c]          : B*T*64
#define XS_OFF (XT_OFF + B_ * T_ * C_)        // ushort xs[b][t][128] hi|lo
#define NSQ_OFF (XS_OFF + B_ * T_ * C_)       // fp32 nsq[b*T+t]
#define WT_OFF (NSQ_OFF + B_ * T_)            // fp32 Wt[m][o], m=k*64+c   : 192*64
#define CAND_OFF (WT_OFF + 192 * O_)          // ushort cand[B*T][64]; slots 0..2 become jsel after refine

__device__ inline ushort bf16_rne(float f) {
    union { float f; unsigned u; } cv; cv.f = f;
    unsigned u = cv.u;
    u += 0x7FFF + ((u >> 16) & 1);
    return (ushort)(u >> 16);
}
__device__ inline float bf16_val(ushort h) {
    union { unsigned u; float f; } cv; cv.u = ((unsigned)h) << 16; return cv.f;
}

// ---------------------------------------------------------------------------
// Prep: x (B,C,T) -> xT (B,T,C) fp32, xs (B,T,128) bf16 [hi|lo], nsq,
//       W (O,C,K) -> Wt[k*64+c][o]   (identical to R4's validated prep)
// ---------------------------------------------------------------------------
__global__ __launch_bounds__(256) void prep_kernel(const float* __restrict__ x,
                                                   const float* __restrict__ W,
                                                   float* __restrict__ ws) {
    float*  xT  = ws + XT_OFF;
    ushort* xs  = (ushort*)(ws + XS_OFF);
    float*  nsq = ws + NSQ_OFF;
    float*  Wt  = ws + WT_OFF;
    int blk = blockIdx.x;
    int tid = threadIdx.x;
    if (blk < B_ * (T_ / 64)) {
        int b  = blk / (T_ / 64);
        int t0 = (blk % (T_ / 64)) * 64;
        __shared__ float tl[64 * 65];
        #pragma unroll
        for (int r = 0; r < 16; ++r) {
            int e = r * 256 + tid;
            int c = e >> 6, t = e & 63;
            tl[c * 65 + t] = x[(b * C_ + c) * T_ + t0 + t];
        }
        __syncthreads();
        #pragma unroll
        for (int r = 0; r < 16; ++r) {
            int e = r * 256 + tid;
            int t = e >> 6, c = e & 63;
            float v = tl[c * 65 + t];
            size_t rowg = (size_t)(b * T_ + t0 + t);
            xT[rowg * 64 + c] = v;
            ushort hi = bf16_rne(v);
            float  fr = v - bf16_val(hi);
            ushort lo = bf16_rne(fr);
            xs[rowg * 128 + c]      = hi;
            xs[rowg * 128 + 64 + c] = lo;
        }
        if (tid < 64) {
            float s = 0.f;
            #pragma unroll
            for (int c = 0; c < 64; ++c) { float v = tl[c * 65 + tid]; s = fmaf(v, v, s); }
            nsq[b * T_ + t0 + tid] = s;
        }
    } else {
        int e = (blk - B_ * (T_ / 64)) * 256 + tid;
        if (e < O_ * C_ * KNN) {
            int o = e / (C_ * KNN);
            int c = (e / KNN) % C_;
            int k = e % KNN;
            Wt[(k * 64 + c) * O_ + o] = W[e];
        }
    }
}

// ---------------------------------------------------------------------------
// KNN screen (MFMA): key = (nsq_i+4) + nsq_j - 2*dot_bf16split, packed with a
// 7-bit (t,reg) id in the low mantissa -> per-lane sorted top-4 via
// 1 fmin + 3 v_med3_f32 per score. j-staging: global_load_lds (no regs, no
// spill) into XOR-swizzled unpadded LDS (conflict-free DMA & reads).
// Grid: bid = m*64 + g, g=(b,h) -> XCD g%8 (j-chunk L2-local). 2048 blocks,
// 18 KB LDS -> 8 blocks/CU.
// ---------------------------------------------------------------------------
__global__ __launch_bounds__(256, 6) void knn_mfma_kernel(const ushort* __restrict__ xs,
                                                          const float* __restrict__ nsq,
                                                          ushort* __restrict__ cand) {
    __shared__ __align__(16) ushort jbuf[64 * 128];   // 16 KB, XOR-swizzled
    __shared__ float nsqs[JCH];                       // 2 KB

    int bid = blockIdx.x;
    int g   = bid & 63;                 // group = b*4 + h  (XCD = g%8)
    int m   = bid >> 6;                 // i-tile 0..31
    int b   = g >> 2, h = g & 3;
    int i0  = m * 64;
    int tid = threadIdx.x;
    int w   = tid >> 6, l = tid & 63, lr = l & 15, lq = l >> 4;
    const ushort* xsb = xs + (size_t)b * T_ * 128;
    int jBase = h * JCH;

    if (tid < 128)
        ((float4*)nsqs)[tid] = ((const float4*)(nsq + b * T_ + jBase))[tid];

    // B-operand (i-side) frags: virtual K-steps [hi0 hi1 hi0 hi1 lo0 lo1]
    short8 bf0, bf1, bf4, bf5;
    {
        const ushort* ib = xsb + (size_t)(i0 + w * 16 + lr) * 128 + lq * 8;
        bf0 = *(const short8*)(ib + 0);
        bf1 = *(const short8*)(ib + 32);
        bf4 = *(const short8*)(ib + 64);
        bf5 = *(const short8*)(ib + 96);
    }
    float ni4 = nsq[b * T_ + i0 + w * 16 + lr] + 4.0f;

    const float INF = __builtin_inff();
    float k0 = INF, k1 = INF, k2 = INF, k3 = INF;   // packed keys, sorted

    const char* jb8 = (const char*)jbuf;

    #pragma unroll 1
    for (int js = 0; js < JCH / 64; ++js) {
        __syncthreads();                              // prev compute done
        #pragma unroll
        for (int q = 0; q < 4; ++q) {                 // DMA 64-row subtile
            int r = w * 16 + q * 4 + lq;
            int c = lr ^ (q * 4 + lq);
            const ushort* gp = xsb + (size_t)(jBase + js * 64 + r) * 128 + c * 8;
            __builtin_amdgcn_global_load_lds(
                (const __attribute__((address_space(1))) void*)gp,
                (__attribute__((address_space(3))) void*)(jbuf + (w * 4 + q) * 512),
                16, 0, 0);
        }
        asm volatile("s_waitcnt vmcnt(0)" ::: "memory");
        __syncthreads();                              // all waves' DMA visible

        #pragma unroll
        for (int tile = 0; tile < 4; ++tile) {
            const char* rowp = jb8 + (tile * 16 + lr) * 256;
            short8 ah0 = *(const short8*)(rowp + ((( 0 + lq) ^ lr) << 4));
            short8 ah1 = *(const short8*)(rowp + ((( 4 + lq) ^ lr) << 4));
            short8 al0 = *(const short8*)(rowp + ((( 8 + lq) ^ lr) << 4));
            short8 al1 = *(const short8*)(rowp + (((12 + lq) ^ lr) << 4));
            f32x4 acc = {0.f, 0.f, 0.f, 0.f};
            acc = __builtin_amdgcn_mfma_f32_16x16x32_bf16(ah0, bf0, acc, 0, 0, 0);
            acc = __builtin_amdgcn_mfma_f32_16x16x32_bf16(ah1, bf1, acc, 0, 0, 0);
            acc = __builtin_amdgcn_mfma_f32_16x16x32_bf16(al0, bf0, acc, 0, 0, 0);
            acc = __builtin_amdgcn_mfma_f32_16x16x32_bf16(al1, bf1, acc, 0, 0, 0);
            acc = __builtin_amdgcn_mfma_f32_16x16x32_bf16(ah0, bf4, acc, 0, 0, 0);
            acc = __builtin_amdgcn_mfma_f32_16x16x32_bf16(ah1, bf5, acc, 0, 0, 0);
            float4 nv = *(const float4*)(nsqs + js * 64 + tile * 16 + lq * 4);
            int idb = (js * 4 + tile) * 4;            // 7-bit id base (uniform)
            #define SCORE1(avl, rr) {                                            \
                float s  = fmaf(-2.f, acc[rr], (avl) + ni4);                     \
                unsigned u = (__float_as_uint(s) & 0xFFFFFF80u) | (unsigned)(idb + rr); \
                float kf = __uint_as_float(u);                                   \
                float n0 = fminf(k0, kf);                                        \
                float n1 = __builtin_amdgcn_fmed3f(k0, k1, kf);                  \
                float n2 = __builtin_amdgcn_fmed3f(k1, k2, kf);                  \
                float n3 = __builtin_amdgcn_fmed3f(k2, k3, kf);                  \
                k0 = n0; k1 = n1; k2 = n2; k3 = n3; }
            SCORE1(nv.x, 0); SCORE1(nv.y, 1); SCORE1(nv.z, 2); SCORE1(nv.w, 3);
            #undef SCORE1
        }
    }

    // decode ids -> j and write 4 candidates (ushort, 8B/lane, full 64B/row/h)
    unsigned u0 = __float_as_uint(k0) & 127u;
    unsigned u1 = __float_as_uint(k1) & 127u;
    unsigned u2 = __float_as_uint(k2) & 127u;
    unsigned u3 = __float_as_uint(k3) & 127u;
    ushortx4 cv;
    cv[0] = (ushort)(jBase + ((u0 >> 2) << 4) + lq * 4 + (u0 & 3));
    cv[1] = (ushort)(jBase + ((u1 >> 2) << 4) + lq * 4 + (u1 & 3));
    cv[2] = (ushort)(jBase + ((u2 >> 2) << 4) + lq * 4 + (u2 & 3));
    cv[3] = (ushort)(jBase + ((u3 >> 2) << 4) + lq * 4 + (u3 & 3));
    int row = b * T_ + i0 + w * 16 + lr;
    *(ushortx4*)(cand + (size_t)row * 64 + h * 16 + lq * 4) = cv;
}

// ---------------------------------------------------------------------------
// Refine: exact fp32 re-rank of 64 candidates/row (R4-validated formula +
// (s,j) lex tie-break == np top_k). Block = 16 rows x 16 threads/row, each
// thread 4 cands. Winners written in-place over cand[row][0..2] (post-barrier).
// ---------------------------------------------------------------------------
__global__ __launch_bounds__(256) void refine_kernel(float* __restrict__ ws) {
    const float* xT  = ws + XT_OFF;
    const float* nsq = ws + NSQ_OFF;
    ushort* cand     = (ushort*)(ws + CAND_OFF);

    __shared__ float  cs[16][48];
    __shared__ ushort cjv[16][48];

    int rl  = threadIdx.x >> 4, sub = threadIdx.x & 15;
    int row = blockIdx.x * 16 + rl;
    int bT  = row & ~(T_ - 1);

    float4 ai[16];
    {
        const float4* rp = (const float4*)(xT + (size_t)row * 64);
        #pragma unroll
        for (int c4 = 0; c4 < 16; ++c4) ai[c4] = rp[c4];
    }
    ushortx4 cl = *(const ushortx4*)(cand + (size_t)row * 64 + sub * 4);

    const float INF = __builtin_inff();
    float D0 = INF, D1 = INF, D2 = INF;
    int   I0 = 0x7FFFFFFF, I1 = 0x7FFFFFFF, I2 = 0x7FFFFFFF;
    #pragma unroll
    for (int t = 0; t < 4; ++t) {
        int j = cl[t];
        const float4* bj = (const float4*)(xT + (size_t)(bT + j) * 64);
        float px = 0.f, py = 0.f, pz = 0.f, pw = 0.f;
        #pragma unroll
        for (int c4 = 0; c4 < 16; ++c4) {
            float4 wv = bj[c4];
            px = fmaf(wv.x, ai[c4].x, px); py = fmaf(wv.y, ai[c4].y, py);
            pz = fmaf(wv.z, ai[c4].z, pz); pw = fmaf(wv.w, ai[c4].w, pw);
        }
        float s = nsq[bT + j] - 2.f * ((px + py) + (pz + pw));
        bool lt2 = (s < D2) || (s == D2 && j < I2);
        if (lt2) {
            bool lt1 = (s < D1) || (s == D1 && j < I1);
            if (lt1) {
                D2 = D1; I2 = I1;
                bool lt0 = (s < D0) || (s == D0 && j < I0);
                if (lt0) { D1 = D0; I1 = I0; D0 = s; I0 = j; }
                else     { D1 = s; I1 = j; }
            } else { D2 = s; I2 = j; }
        }
    }
    cs[rl][sub * 3 + 0] = D0; cjv[rl][sub * 3 + 0] = (ushort)I0;
    cs[rl][sub * 3 + 1] = D1; cjv[rl][sub * 3 + 1] = (ushort)I1;
    cs[rl][sub * 3 + 2] = D2; cjv[rl][sub * 3 + 2] = (ushort)I2;
    __syncthreads();
    if (sub == 0) {
        float E0 = INF, E1 = INF, E2 = INF;
        int   J0 = 0x7FFFFFFF, J1 = 0x7FFFFFFF, J2 = 0x7FFFFFFF;
        #pragma unroll
        for (int q = 0; q < 48; ++q) {
            float s = cs[rl][q]; int j = cjv[rl][q];
            bool lt2 = (s < E2) || (s == E2 && j < J2);
            if (lt2) {
                bool lt1 = (s < E1) || (s == E1 && j < J1);
                if (lt1) {
                    E2 = E1; J2 = J1;
                    bool lt0 = (s < E0) || (s == E0 && j < J0);
                    if (lt0) { E1 = E0; J1 = J0; E0 = s; J0 = j; }
                    else     { E1 = s; J1 = j; }
                } else { E2 = s; J2 = j; }
            }
        }
        ushort* dst = cand + (size_t)row * 64;
        dst[0] = (ushort)J0; dst[1] = (ushort)J1; dst[2] = (ushort)J2;
    }
}

// ---------------------------------------------------------------------------
// Conv: block = (b, 32-i tile), 256 threads, 1024 blocks. Only g (24 KB) in
// LDS; Wt read from global (L1/L2 broadcast). Per-(o,i) accumulation order
// identical to R2/R4 (bitwise-same output). Coalesced float4 stores.
// ---------------------------------------------------------------------------
__global__ __launch_bounds__(256) void conv2_kernel(const float* __restrict__ ws,
                                                    const float* __restrict__ bias,
                                                    float* __restrict__ out) {
    const float*  xT   = ws + XT_OFF;
    const float*  Wt   = ws + WT_OFF;
    const ushort* cand = (const ushort*)(ws + CAND_OFF);

    __shared__ float g_s[192 * 32];

    int b   = blockIdx.x >> 6;
    int i0  = (blockIdx.x & 63) * 32;
    int tid = threadIdx.x;

    if (tid < 96) {          // gather 3 neighbor rows per i' -> g_s[m][i']
        int k  = tid >> 5;
        int ip = tid & 31;
        int j  = cand[(size_t)(b * T_ + i0 + ip) * 64 + k];
        const float4* src = (const float4*)(xT + ((size_t)b * T_ + j) * 64);
        #pragma unroll
        for (int c4 = 0; c4 < 16; ++c4) {
            float4 v = src[c4];
            int mm = k * 64 + c4 * 4;
            g_s[(mm + 0) * 32 + ip] = v.x;
            g_s[(mm + 1) * 32 + ip] = v.y;
            g_s[(mm + 2) * 32 + ip] = v.z;
            g_s[(mm + 3) * 32 + ip] = v.w;
        }
    }
    __syncthreads();

    int oq = tid >> 3;        // o = oq*2, oq*2+1
    int iq = tid & 7;         // i' = iq*4 .. +3
    float a0x = 0.f, a0y = 0.f, a0z = 0.f, a0w = 0.f;
    float a1x = 0.f, a1y = 0.f, a1z = 0.f, a1w = 0.f;
    #pragma unroll 4
    for (int mm = 0; mm < 192; ++mm) {
        float2 wv = *(const float2*)(Wt + mm * 64 + oq * 2);   // L1 broadcast
        float4 gv = *(const float4*)(g_s + mm * 32 + iq * 4);  // LDS broadcast
        a0x = fmaf(wv.x, gv.x, a0x); a0y = fmaf(wv.x, gv.y, a0y);
        a0z = fmaf(wv.x, gv.z, a0z); a0w = fmaf(wv.x, gv.w, a0w);
        a1x = fmaf(wv.y, gv.x, a1x); a1y = fmaf(wv.y, gv.y, a1y);
        a1z = fmaf(wv.y, gv.z, a1z); a1w = fmaf(wv.y, gv.w, a1w);
    }
    int o0 = oq * 2;
    float b0 = bias[o0], b1 = bias[o0 + 1];
    float4 r0; r0.x = a0x + b0; r0.y = a0y + b0; r0.z = a0z + b0; r0.w = a0w + b0;
    float4 r1; r1.x = a1x + b1; r1.y = a1y + b1; r1.z = a1z + b1; r1.w = a1w + b1;
    *(float4*)(out + ((size_t)b * O_ + o0)     * T_ + i0 + iq * 4) = r0;
    *(float4*)(out + ((size_t)b * O_ + o0 + 1) * T_ + i0 + iq * 4) = r1;
}

// ---------------------------------------------------------------------------
extern "C" void kernel_launch(void* const* d_in, const int* in_sizes, int n_in,
                              void* d_out, int out_size, void* d_ws, size_t ws_size,
                              hipStream_t stream) {
    const float* x    = (const float*)d_in[0];
    const float* W    = (const float*)d_in[1];
    const float* bias = (const float*)d_in[2];
    float* out = (float*)d_out;
    float* ws  = (float*)d_ws;
    // requires 21.2 MB workspace (same footprint as R4, proven)

    prep_kernel<<<B_ * (T_ / 64) + 48, 256, 0, stream>>>(x, W, ws);
    knn_mfma_kernel<<<2048, 256, 0, stream>>>(
        (const ushort*)(ws + XS_OFF), ws + NSQ_OFF, (ushort*)(ws + CAND_OFF));
    refine_kernel<<<B_ * T_ / 16, 256, 0, stream>>>(ws);
    conv2_kernel<<<B_ * 64, 256, 0, stream>>>(ws, bias, out);
}

// Round 6
// 142.095 us; speedup vs baseline: 1.5163x; 1.5163x over previous
//
#include <hip/hip_runtime.h>

// Problem constants (fixed by reference)
#define B_ 16
#define C_ 64
#define T_ 2048
#define O_ 64
#define KNN 3
#define HSPLIT 4
#define JCH (T_ / HSPLIT)     // 512 j per (b,h) chunk

typedef short short8   __attribute__((ext_vector_type(8)));   // 8 bf16
typedef float f32x4    __attribute__((ext_vector_type(4)));
typedef unsigned short ushortx4 __attribute__((ext_vector_type(4)));

// Workspace layout (float slots). Total ~18 MB (< 21.2 MB proven footprint).
#define XT_OFF 0                              // fp32 xT[b][t][c]          : B*T*64
#define XS_OFF (XT_OFF + B_ * T_ * C_)        // ushort xs[b][t][128] hi|lo
#define NSQ_OFF (XS_OFF + B_ * T_ * C_)       // fp32 nsq[b*T+t]
#define WT_OFF (NSQ_OFF + B_ * T_)            // fp32 Wt[m][o], m=k*64+c   : 192*64
#define CAND_OFF (WT_OFF + 192 * O_)          // ushort cand[B*T][16]; slots 0..2 become jsel after refine

__device__ inline ushort bf16_rne(float f) {
    union { float f; unsigned u; } cv; cv.f = f;
    unsigned u = cv.u;
    u += 0x7FFF + ((u >> 16) & 1);
    return (ushort)(u >> 16);
}
__device__ inline float bf16_val(ushort h) {
    union { unsigned u; float f; } cv; cv.u = ((unsigned)h) << 16; return cv.f;
}

// ---------------------------------------------------------------------------
// Prep (validated R4/R5): x (B,C,T) -> xT (B,T,C) fp32, xs bf16 [hi|lo], nsq,
//       W (O,C,K) -> Wt[k*64+c][o]
// ---------------------------------------------------------------------------
__global__ __launch_bounds__(256) void prep_kernel(const float* __restrict__ x,
                                                   const float* __restrict__ W,
                                                   float* __restrict__ ws) {
    float*  xT  = ws + XT_OFF;
    ushort* xs  = (ushort*)(ws + XS_OFF);
    float*  nsq = ws + NSQ_OFF;
    float*  Wt  = ws + WT_OFF;
    int blk = blockIdx.x;
    int tid = threadIdx.x;
    if (blk < B_ * (T_ / 64)) {
        int b  = blk / (T_ / 64);
        int t0 = (blk % (T_ / 64)) * 64;
        __shared__ float tl[64 * 65];
        #pragma unroll
        for (int r = 0; r < 16; ++r) {
            int e = r * 256 + tid;
            int c = e >> 6, t = e & 63;
            tl[c * 65 + t] = x[(b * C_ + c) * T_ + t0 + t];
        }
        __syncthreads();
        #pragma unroll
        for (int r = 0; r < 16; ++r) {
            int e = r * 256 + tid;
            int t = e >> 6, c = e & 63;
            float v = tl[c * 65 + t];
            size_t rowg = (size_t)(b * T_ + t0 + t);
            xT[rowg * 64 + c] = v;
            ushort hi = bf16_rne(v);
            float  fr = v - bf16_val(hi);
            ushort lo = bf16_rne(fr);
            xs[rowg * 128 + c]      = hi;
            xs[rowg * 128 + 64 + c] = lo;
        }
        if (tid < 64) {
            float s = 0.f;
            #pragma unroll
            for (int c = 0; c < 64; ++c) { float v = tl[c * 65 + tid]; s = fmaf(v, v, s); }
            nsq[b * T_ + t0 + tid] = s;
        }
    } else {
        int e = (blk - B_ * (T_ / 64)) * 256 + tid;
        if (e < O_ * C_ * KNN) {
            int o = e / (C_ * KNN);
            int c = (e / KNN) % C_;
            int k = e % KNN;
            Wt[(k * 64 + c) * O_ + o] = W[e];
        }
    }
}

// ---------------------------------------------------------------------------
// KNN screen (MFMA). Block = (b,h) x 128-i tile, 4 waves; wave owns 32 i-rows
// (two 16-row B-frag sets -> 4 ds_read feed 12 MFMA). j staged 32 rows/round,
// DOUBLE-BUFFERED global_load_lds: DMA(n+1) issued after barrier(n), so it
// overlaps compute(n); vmcnt(0) at round top waits only the needed buffer.
// Keys pack 9-bit id (stripe 7b + lq 2b) into mantissa; per-lane sorted top-4
// via fmin+3*med3. Epilogue merges 4 lq-stripes -> 4 candidates per (row,h).
// ---------------------------------------------------------------------------
__global__ __launch_bounds__(256, 4) void knn_mfma_kernel(const ushort* __restrict__ xs,
                                                          const float* __restrict__ nsq,
                                                          ushort* __restrict__ cand) {
    __shared__ __align__(16) ushort jbuf[2][32 * 128];   // 2 x 8 KB, XOR-swizzled
    __shared__ float nsqs[JCH];                          // 2 KB

    int bid = blockIdx.x;
    int g   = bid & 63;                 // group = b*4 + h  (XCD = g%8)
    int m   = bid >> 6;                 // i-tile 0..15 (128 rows each)
    int b   = g >> 2, h = g & 3;
    int i0  = m * 128;
    int tid = threadIdx.x;
    int w   = tid >> 6, l = tid & 63, lr = l & 15, lq = l >> 4;
    const ushort* xsb = xs + (size_t)b * T_ * 128;
    int jBase = h * JCH;

    if (tid < 128)
        ((float4*)nsqs)[tid] = ((const float4*)(nsq + b * T_ + jBase))[tid];

    // B-operand frags for 2 i-sets: rows i0+w*32+lr (A) and +16 (B)
    short8 bA0, bA1, bA4, bA5, bB0, bB1, bB4, bB5;
    {
        const ushort* ia = xsb + (size_t)(i0 + w * 32 + lr) * 128 + lq * 8;
        bA0 = *(const short8*)(ia + 0);  bA1 = *(const short8*)(ia + 32);
        bA4 = *(const short8*)(ia + 64); bA5 = *(const short8*)(ia + 96);
        const ushort* ib2 = ia + 16 * 128;
        bB0 = *(const short8*)(ib2 + 0);  bB1 = *(const short8*)(ib2 + 32);
        bB4 = *(const short8*)(ib2 + 64); bB5 = *(const short8*)(ib2 + 96);
    }
    float niA = nsq[b * T_ + i0 + w * 32 + lr] + 4.0f;
    float niB = nsq[b * T_ + i0 + w * 32 + 16 + lr] + 4.0f;

    const float INF = __builtin_inff();
    float kA0 = INF, kA1 = INF, kA2 = INF, kA3 = INF;
    float kB0 = INF, kB1 = INF, kB2 = INF, kB3 = INF;

    // DMA one 32-row subtile (8 KB): 2 issues/thread, swizzled slot = c ^ (r&15)
    int cSw = lr ^ (w * 4 + lq);                 // source chunk for this lane
    #define ISSUE_DMA(jsv, bufv) {                                               \
        _Pragma("unroll")                                                        \
        for (int p = 0; p < 2; ++p) {                                            \
            int rloc = p * 16 + w * 4 + lq;                                      \
            const ushort* gp = xsb + (size_t)(jBase + (jsv) * 32 + rloc) * 128 + cSw * 8; \
            __builtin_amdgcn_global_load_lds(                                    \
                (const __attribute__((address_space(1))) void*)gp,               \
                (__attribute__((address_space(3))) void*)(jbuf[bufv] + (p * 16 + w * 4) * 128), \
                16, 0, 0);                                                       \
        } }

    ISSUE_DMA(0, 0);

    #pragma unroll 1
    for (int js = 0; js < 16; ++js) {
        asm volatile("s_waitcnt vmcnt(0)" ::: "memory");  // my round-js DMA done
        __syncthreads();                                  // everyone's done; buf[(js+1)&1] free
        if (js < 15) ISSUE_DMA(js + 1, (js + 1) & 1);     // overlaps compute below
        const char* jb8 = (const char*)jbuf[js & 1];
        #pragma unroll
        for (int tile = 0; tile < 2; ++tile) {
            const char* rowp = jb8 + (tile * 16 + lr) * 256;
            short8 ah0 = *(const short8*)(rowp + ((( 0 + lq) ^ lr) << 4));
            short8 ah1 = *(const short8*)(rowp + ((( 4 + lq) ^ lr) << 4));
            short8 al0 = *(const short8*)(rowp + ((( 8 + lq) ^ lr) << 4));
            short8 al1 = *(const short8*)(rowp + (((12 + lq) ^ lr) << 4));
            f32x4 accA = {0.f, 0.f, 0.f, 0.f};
            f32x4 accB = {0.f, 0.f, 0.f, 0.f};
            accA = __builtin_amdgcn_mfma_f32_16x16x32_bf16(ah0, bA0, accA, 0, 0, 0);
            accB = __builtin_amdgcn_mfma_f32_16x16x32_bf16(ah0, bB0, accB, 0, 0, 0);
            accA = __builtin_amdgcn_mfma_f32_16x16x32_bf16(ah1, bA1, accA, 0, 0, 0);
            accB = __builtin_amdgcn_mfma_f32_16x16x32_bf16(ah1, bB1, accB, 0, 0, 0);
            accA = __builtin_amdgcn_mfma_f32_16x16x32_bf16(al0, bA0, accA, 0, 0, 0);
            accB = __builtin_amdgcn_mfma_f32_16x16x32_bf16(al0, bB0, accB, 0, 0, 0);
            accA = __builtin_amdgcn_mfma_f32_16x16x32_bf16(al1, bA1, accA, 0, 0, 0);
            accB = __builtin_amdgcn_mfma_f32_16x16x32_bf16(al1, bB1, accB, 0, 0, 0);
            accA = __builtin_amdgcn_mfma_f32_16x16x32_bf16(ah0, bA4, accA, 0, 0, 0);
            accB = __builtin_amdgcn_mfma_f32_16x16x32_bf16(ah0, bB4, accB, 0, 0, 0);
            accA = __builtin_amdgcn_mfma_f32_16x16x32_bf16(ah1, bA5, accA, 0, 0, 0);
            accB = __builtin_amdgcn_mfma_f32_16x16x32_bf16(ah1, bB5, accB, 0, 0, 0);
            float4 nv = *(const float4*)(nsqs + js * 32 + tile * 16 + lq * 4);
            int idb = ((js * 2 + tile) << 2) | (lq << 7);   // 9-bit id base
            #define INS(K0, K1, K2, K3, sv, idv) {                                  \
                unsigned uu = (__float_as_uint(sv) & 0xFFFFFE00u) | (unsigned)(idv); \
                float kf = __uint_as_float(uu);                                      \
                float n0 = fminf(K0, kf);                                            \
                float n1 = __builtin_amdgcn_fmed3f(K0, K1, kf);                      \
                float n2 = __builtin_amdgcn_fmed3f(K1, K2, kf);                      \
                float n3 = __builtin_amdgcn_fmed3f(K2, K3, kf);                      \
                K0 = n0; K1 = n1; K2 = n2; K3 = n3; }
            {
                float s0 = fmaf(-2.f, accA[0], nv.x + niA); INS(kA0, kA1, kA2, kA3, s0, idb + 0);
                float s1 = fmaf(-2.f, accA[1], nv.y + niA); INS(kA0, kA1, kA2, kA3, s1, idb + 1);
                float s2 = fmaf(-2.f, accA[2], nv.z + niA); INS(kA0, kA1, kA2, kA3, s2, idb + 2);
                float s3 = fmaf(-2.f, accA[3], nv.w + niA); INS(kA0, kA1, kA2, kA3, s3, idb + 3);
            }
            {
                float s0 = fmaf(-2.f, accB[0], nv.x + niB); INS(kB0, kB1, kB2, kB3, s0, idb + 0);
                float s1 = fmaf(-2.f, accB[1], nv.y + niB); INS(kB0, kB1, kB2, kB3, s1, idb + 1);
                float s2 = fmaf(-2.f, accB[2], nv.z + niB); INS(kB0, kB1, kB2, kB3, s2, idb + 2);
                float s3 = fmaf(-2.f, accB[3], nv.w + niB); INS(kB0, kB1, kB2, kB3, s3, idb + 3);
            }
            #undef INS
        }
    }

    // Epilogue: merge 4 lq-stripes per row -> top-4 of 16, decode, write cand.
    __syncthreads();
    float* fbuf = (float*)jbuf;                 // 128 rows x 16 keys = 8 KB
    {
        float* pa = fbuf + (w * 32 + lr) * 16 + lq * 4;
        pa[0] = kA0; pa[1] = kA1; pa[2] = kA2; pa[3] = kA3;
        float* pb = fbuf + (w * 32 + 16 + lr) * 16 + lq * 4;
        pb[0] = kB0; pb[1] = kB1; pb[2] = kB2; pb[3] = kB3;
    }
    __syncthreads();
    if (l < 32) {
        int rloc = w * 32 + l;
        const float* pr = fbuf + rloc * 16;
        float m0 = INF, m1 = INF, m2 = INF, m3 = INF;
        #pragma unroll
        for (int q2 = 0; q2 < 16; ++q2) {
            float kf = pr[q2];
            float n0 = fminf(m0, kf);
            float n1 = __builtin_amdgcn_fmed3f(m0, m1, kf);
            float n2 = __builtin_amdgcn_fmed3f(m1, m2, kf);
            float n3 = __builtin_amdgcn_fmed3f(m2, m3, kf);
            m0 = n0; m1 = n1; m2 = n2; m3 = n3;
        }
        ushortx4 cv;
        #define DEC(mf, slot) { unsigned u = __float_as_uint(mf) & 511u;             \
            cv[slot] = (ushort)(jBase + (((u & 127u) >> 2) << 4) + ((u >> 7) << 2) + (u & 3)); }
        DEC(m0, 0); DEC(m1, 1); DEC(m2, 2); DEC(m3, 3);
        #undef DEC
        int row = b * T_ + i0 + rloc;
        *(ushortx4*)(cand + (size_t)row * 16 + h * 4) = cv;
    }
}

// ---------------------------------------------------------------------------
// Refine v2: exact fp32 re-rank, cooperative. Quarter-wave per row; lane lr
// holds ai[lr*4..+3]; per candidate the 16 lanes load the j-row COALESCED,
// 4 FMA + 4-step shfl_xor butterfly (bitwise-identical in all lanes), then
// branchless (s,j)-lex top-3. Winners -> cand[row][0..2] (own row, post-read).
// ---------------------------------------------------------------------------
__global__ __launch_bounds__(256) void refine_kernel(float* __restrict__ ws) {
    const float* xT  = ws + XT_OFF;
    const float* nsq = ws + NSQ_OFF;
    ushort* cand     = (ushort*)(ws + CAND_OFF);

    int tid = threadIdx.x;
    int w = tid >> 6, l = tid & 63, qw = l >> 4, lr = l & 15;
    int row = blockIdx.x * 16 + w * 4 + qw;
    int bT  = row & ~(T_ - 1);

    float4 av = *(const float4*)(xT + (size_t)row * 64 + lr * 4);
    int jown = cand[(size_t)row * 16 + lr];

    const float INF = __builtin_inff();
    float D0 = INF, D1 = INF, D2 = INF;
    int   I0 = 0x7FFFFFFF, I1 = 0x7FFFFFFF, I2 = 0x7FFFFFFF;

    #pragma unroll
    for (int t = 0; t < 16; ++t) {
        int jt = __shfl(jown, (l & 48) + t, 64);          // broadcast cand t of group
        float4 bv = *(const float4*)(xT + (size_t)(bT + jt) * 64 + lr * 4);
        float p = fmaf(bv.w, av.w, fmaf(bv.z, av.z, fmaf(bv.y, av.y, bv.x * av.x)));
        p += __shfl_xor(p, 1, 64);
        p += __shfl_xor(p, 2, 64);
        p += __shfl_xor(p, 4, 64);
        p += __shfl_xor(p, 8, 64);
        float s = nsq[bT + jt] - 2.f * p;
        bool lt2 = (s < D2) || (s == D2 && jt < I2);
        bool lt1 = (s < D1) || (s == D1 && jt < I1);
        bool lt0 = (s < D0) || (s == D0 && jt < I0);
        float nD2 = lt1 ? D1 : (lt2 ? s : D2); int nI2 = lt1 ? I1 : (lt2 ? jt : I2);
        float nD1 = lt0 ? D0 : (lt1 ? s : D1); int nI1 = lt0 ? I0 : (lt1 ? jt : I1);
        D2 = nD2; I2 = nI2; D1 = nD1; I1 = nI1;
        D0 = lt0 ? s : D0; I0 = lt0 ? jt : I0;
    }
    if (lr == 0) {
        ushort* dst = cand + (size_t)row * 16;
        dst[0] = (ushort)I0; dst[1] = (ushort)I1; dst[2] = (ushort)I2;
    }
}

// ---------------------------------------------------------------------------
// Conv (R5-validated math): block = (b, 32-i tile), 256 threads, 1024 blocks.
// g (24 KB) in LDS; Wt from global (L1 broadcast). Coalesced float4 stores.
// ---------------------------------------------------------------------------
__global__ __launch_bounds__(256) void conv2_kernel(const float* __restrict__ ws,
                                                    const float* __restrict__ bias,
                                                    float* __restrict__ out) {
    const float*  xT   = ws + XT_OFF;
    const float*  Wt   = ws + WT_OFF;
    const ushort* cand = (const ushort*)(ws + CAND_OFF);

    __shared__ float g_s[192 * 32];

    int b   = blockIdx.x >> 6;
    int i0  = (blockIdx.x & 63) * 32;
    int tid = threadIdx.x;

    if (tid < 96) {
        int k  = tid >> 5;
        int ip = tid & 31;
        int j  = cand[(size_t)(b * T_ + i0 + ip) * 16 + k];
        const float4* src = (const float4*)(xT + ((size_t)b * T_ + j) * 64);
        #pragma unroll
        for (int c4 = 0; c4 < 16; ++c4) {
            float4 v = src[c4];
            int mm = k * 64 + c4 * 4;
            g_s[(mm + 0) * 32 + ip] = v.x;
            g_s[(mm + 1) * 32 + ip] = v.y;
            g_s[(mm + 2) * 32 + ip] = v.z;
            g_s[(mm + 3) * 32 + ip] = v.w;
        }
    }
    __syncthreads();

    int oq = tid >> 3;
    int iq = tid & 7;
    float a0x = 0.f, a0y = 0.f, a0z = 0.f, a0w = 0.f;
    float a1x = 0.f, a1y = 0.f, a1z = 0.f, a1w = 0.f;
    #pragma unroll 4
    for (int mm = 0; mm < 192; ++mm) {
        float2 wv = *(const float2*)(Wt + mm * 64 + oq * 2);
        float4 gv = *(const float4*)(g_s + mm * 32 + iq * 4);
        a0x = fmaf(wv.x, gv.x, a0x); a0y = fmaf(wv.x, gv.y, a0y);
        a0z = fmaf(wv.x, gv.z, a0z); a0w = fmaf(wv.x, gv.w, a0w);
        a1x = fmaf(wv.y, gv.x, a1x); a1y = fmaf(wv.y, gv.y, a1y);
        a1z = fmaf(wv.y, gv.z, a1z); a1w = fmaf(wv.y, gv.w, a1w);
    }
    int o0 = oq * 2;
    float b0 = bias[o0], b1 = bias[o0 + 1];
    float4 r0; r0.x = a0x + b0; r0.y = a0y + b0; r0.z = a0z + b0; r0.w = a0w + b0;
    float4 r1; r1.x = a1x + b1; r1.y = a1y + b1; r1.z = a1z + b1; r1.w = a1w + b1;
    *(float4*)(out + ((size_t)b * O_ + o0)     * T_ + i0 + iq * 4) = r0;
    *(float4*)(out + ((size_t)b * O_ + o0 + 1) * T_ + i0 + iq * 4) = r1;
}

// ---------------------------------------------------------------------------
extern "C" void kernel_launch(void* const* d_in, const int* in_sizes, int n_in,
                              void* d_out, int out_size, void* d_ws, size_t ws_size,
                              hipStream_t stream) {
    const float* x    = (const float*)d_in[0];
    const float* W    = (const float*)d_in[1];
    const float* bias = (const float*)d_in[2];
    float* out = (float*)d_out;
    float* ws  = (float*)d_ws;
    // requires ~18 MB workspace (<= 21.2 MB proven)

    prep_kernel<<<B_ * (T_ / 64) + 48, 256, 0, stream>>>(x, W, ws);
    knn_mfma_kernel<<<1024, 256, 0, stream>>>(
        (const ushort*)(ws + XS_OFF), ws + NSQ_OFF, (ushort*)(ws + CAND_OFF));
    refine_kernel<<<B_ * T_ / 16, 256, 0, stream>>>(ws);
    conv2_kernel<<<B_ * 64, 256, 0, stream>>>(ws, bias, out);
}

// Round 7
// 139.552 us; speedup vs baseline: 1.5440x; 1.0182x over previous
//
#include <hip/hip_runtime.h>

// Problem constants (fixed by reference)
#define B_ 16
#define C_ 64
#define T_ 2048
#define O_ 64
#define KNN 3
#define HSPLIT 2
#define JCH (T_ / HSPLIT)     // 1024 j per (b,h) chunk

typedef short short8   __attribute__((ext_vector_type(8)));   // 8 bf16
typedef float f32x4    __attribute__((ext_vector_type(4)));
typedef unsigned short ushortx4 __attribute__((ext_vector_type(4)));

// Workspace layout (float slots). Total ~17.5 MB (< 21.2 MB proven footprint).
#define XT_OFF 0                              // fp32 xT[b][t][c]          : B*T*64
#define XS_OFF (XT_OFF + B_ * T_ * C_)        // ushort xs[b][t][128] hi|lo
#define NSQ_OFF (XS_OFF + B_ * T_ * C_)       // fp32 nsq[b*T+t]
#define WT_OFF (NSQ_OFF + B_ * T_)            // fp32 Wt[m][o], m=k*64+c   : 192*64
#define CAND_OFF (WT_OFF + 192 * O_)          // ushort cand[B*T][8]

__device__ inline ushort bf16_rne(float f) {
    union { float f; unsigned u; } cv; cv.f = f;
    unsigned u = cv.u;
    u += 0x7FFF + ((u >> 16) & 1);
    return (ushort)(u >> 16);
}
__device__ inline float bf16_val(ushort h) {
    union { unsigned u; float f; } cv; cv.u = ((unsigned)h) << 16; return cv.f;
}

// ---------------------------------------------------------------------------
// Prep (validated R4-R6): x (B,C,T) -> xT (B,T,C) fp32, xs bf16 [hi|lo], nsq,
//       W (O,C,K) -> Wt[k*64+c][o]
// ---------------------------------------------------------------------------
__global__ __launch_bounds__(256) void prep_kernel(const float* __restrict__ x,
                                                   const float* __restrict__ W,
                                                   float* __restrict__ ws) {
    float*  xT  = ws + XT_OFF;
    ushort* xs  = (ushort*)(ws + XS_OFF);
    float*  nsq = ws + NSQ_OFF;
    float*  Wt  = ws + WT_OFF;
    int blk = blockIdx.x;
    int tid = threadIdx.x;
    if (blk < B_ * (T_ / 64)) {
        int b  = blk / (T_ / 64);
        int t0 = (blk % (T_ / 64)) * 64;
        __shared__ float tl[64 * 65];
        #pragma unroll
        for (int r = 0; r < 16; ++r) {
            int e = r * 256 + tid;
            int c = e >> 6, t = e & 63;
            tl[c * 65 + t] = x[(b * C_ + c) * T_ + t0 + t];
        }
        __syncthreads();
        #pragma unroll
        for (int r = 0; r < 16; ++r) {
            int e = r * 256 + tid;
            int t = e >> 6, c = e & 63;
            float v = tl[c * 65 + t];
            size_t rowg = (size_t)(b * T_ + t0 + t);
            xT[rowg * 64 + c] = v;
            ushort hi = bf16_rne(v);
            float  fr = v - bf16_val(hi);
            ushort lo = bf16_rne(fr);
            xs[rowg * 128 + c]      = hi;
            xs[rowg * 128 + 64 + c] = lo;
        }
        if (tid < 64) {
            float s = 0.f;
            #pragma unroll
            for (int c = 0; c < 64; ++c) { float v = tl[c * 65 + tid]; s = fmaf(v, v, s); }
            nsq[b * T_ + t0 + tid] = s;
        }
    } else {
        int e = (blk - B_ * (T_ / 64)) * 256 + tid;
        if (e < O_ * C_ * KNN) {
            int o = e / (C_ * KNN);
            int c = (e / KNN) % C_;
            int k = e % KNN;
            Wt[(k * 64 + c) * O_ + o] = W[e];
        }
    }
}

// ---------------------------------------------------------------------------
// KNN screen v3 (MFMA). HSPLIT=2: each staged 32-row j-subtile feeds a 128-i
// tile -> LDS-pipe + DMA traffic per j processed is HALF of R6. Double-
// buffered global_load_lds (issue n+1 after barrier n). 10-bit ids in the
// mantissa; per-lane sorted top-4 via fmin+3*med3; epilogue merges 4
// lq-stripes -> 4 cands per (row, half). 512 blocks = 2/CU.
// ---------------------------------------------------------------------------
__global__ __launch_bounds__(256, 4) void knn_mfma_kernel(const ushort* __restrict__ xs,
                                                          const float* __restrict__ nsq,
                                                          ushort* __restrict__ cand) {
    __shared__ __align__(16) ushort jbuf[2][32 * 128];   // 2 x 8 KB, XOR-swizzled
    __shared__ float nsqs[JCH];                          // 4 KB

    int bid = blockIdx.x;
    int g   = bid & 31;                 // group = b*2 + h  (XCD = g%8)
    int m   = bid >> 5;                 // i-tile 0..15 (128 rows each)
    int b   = g >> 1, h = g & 1;
    int i0  = m * 128;
    int tid = threadIdx.x;
    int w   = tid >> 6, l = tid & 63, lr = l & 15, lq = l >> 4;
    const ushort* xsb = xs + (size_t)b * T_ * 128;
    int jBase = h * JCH;

    ((float4*)nsqs)[tid] = ((const float4*)(nsq + b * T_ + jBase))[tid];

    // B-operand frags for 2 i-sets: rows i0+w*32+lr (A) and +16 (B)
    short8 bA0, bA1, bA4, bA5, bB0, bB1, bB4, bB5;
    {
        const ushort* ia = xsb + (size_t)(i0 + w * 32 + lr) * 128 + lq * 8;
        bA0 = *(const short8*)(ia + 0);  bA1 = *(const short8*)(ia + 32);
        bA4 = *(const short8*)(ia + 64); bA5 = *(const short8*)(ia + 96);
        const ushort* ib2 = ia + 16 * 128;
        bB0 = *(const short8*)(ib2 + 0);  bB1 = *(const short8*)(ib2 + 32);
        bB4 = *(const short8*)(ib2 + 64); bB5 = *(const short8*)(ib2 + 96);
    }
    float niA = nsq[b * T_ + i0 + w * 32 + lr] + 4.0f;
    float niB = nsq[b * T_ + i0 + w * 32 + 16 + lr] + 4.0f;

    const float INF = __builtin_inff();
    float kA0 = INF, kA1 = INF, kA2 = INF, kA3 = INF;
    float kB0 = INF, kB1 = INF, kB2 = INF, kB3 = INF;

    int cSw = lr ^ (w * 4 + lq);                 // swizzled source chunk
    #define ISSUE_DMA(jsv, bufv) {                                               \
        _Pragma("unroll")                                                        \
        for (int p = 0; p < 2; ++p) {                                            \
            int rloc = p * 16 + w * 4 + lq;                                      \
            const ushort* gp = xsb + (size_t)(jBase + (jsv) * 32 + rloc) * 128 + cSw * 8; \
            __builtin_amdgcn_global_load_lds(                                    \
                (const __attribute__((address_space(1))) void*)gp,               \
                (__attribute__((address_space(3))) void*)(jbuf[bufv] + (p * 16 + w * 4) * 128), \
                16, 0, 0);                                                       \
        } }

    ISSUE_DMA(0, 0);

    #pragma unroll 1
    for (int js = 0; js < 32; ++js) {
        asm volatile("s_waitcnt vmcnt(0)" ::: "memory");  // my round-js DMA done
        __syncthreads();                                  // all DMA visible; other buf free
        if (js < 31) ISSUE_DMA(js + 1, (js + 1) & 1);     // overlaps compute below
        const char* jb8 = (const char*)jbuf[js & 1];
        #pragma unroll
        for (int tile = 0; tile < 2; ++tile) {
            const char* rowp = jb8 + (tile * 16 + lr) * 256;
            short8 ah0 = *(const short8*)(rowp + ((( 0 + lq) ^ lr) << 4));
            short8 ah1 = *(const short8*)(rowp + ((( 4 + lq) ^ lr) << 4));
            short8 al0 = *(const short8*)(rowp + ((( 8 + lq) ^ lr) << 4));
            short8 al1 = *(const short8*)(rowp + (((12 + lq) ^ lr) << 4));
            f32x4 accA = {0.f, 0.f, 0.f, 0.f};
            f32x4 accB = {0.f, 0.f, 0.f, 0.f};
            accA = __builtin_amdgcn_mfma_f32_16x16x32_bf16(ah0, bA0, accA, 0, 0, 0);
            accB = __builtin_amdgcn_mfma_f32_16x16x32_bf16(ah0, bB0, accB, 0, 0, 0);
            accA = __builtin_amdgcn_mfma_f32_16x16x32_bf16(ah1, bA1, accA, 0, 0, 0);
            accB = __builtin_amdgcn_mfma_f32_16x16x32_bf16(ah1, bB1, accB, 0, 0, 0);
            accA = __builtin_amdgcn_mfma_f32_16x16x32_bf16(al0, bA0, accA, 0, 0, 0);
            accB = __builtin_amdgcn_mfma_f32_16x16x32_bf16(al0, bB0, accB, 0, 0, 0);
            accA = __builtin_amdgcn_mfma_f32_16x16x32_bf16(al1, bA1, accA, 0, 0, 0);
            accB = __builtin_amdgcn_mfma_f32_16x16x32_bf16(al1, bB1, accB, 0, 0, 0);
            accA = __builtin_amdgcn_mfma_f32_16x16x32_bf16(ah0, bA4, accA, 0, 0, 0);
            accB = __builtin_amdgcn_mfma_f32_16x16x32_bf16(ah0, bB4, accB, 0, 0, 0);
            accA = __builtin_amdgcn_mfma_f32_16x16x32_bf16(ah1, bA5, accA, 0, 0, 0);
            accB = __builtin_amdgcn_mfma_f32_16x16x32_bf16(ah1, bB5, accB, 0, 0, 0);
            float4 nv = *(const float4*)(nsqs + js * 32 + tile * 16 + lq * 4);
            int idb = ((js * 2 + tile) << 2) | (lq << 8);   // 10-bit id base
            #define INS(K0, K1, K2, K3, sv, idv) {                                  \
                unsigned uu = (__float_as_uint(sv) & 0xFFFFFC00u) | (unsigned)(idv); \
                float kf = __uint_as_float(uu);                                      \
                float n0 = fminf(K0, kf);                                            \
                float n1 = __builtin_amdgcn_fmed3f(K0, K1, kf);                      \
                float n2 = __builtin_amdgcn_fmed3f(K1, K2, kf);                      \
                float n3 = __builtin_amdgcn_fmed3f(K2, K3, kf);                      \
                K0 = n0; K1 = n1; K2 = n2; K3 = n3; }
            {
                float s0 = fmaf(-2.f, accA[0], nv.x + niA); INS(kA0, kA1, kA2, kA3, s0, idb + 0);
                float s1 = fmaf(-2.f, accA[1], nv.y + niA); INS(kA0, kA1, kA2, kA3, s1, idb + 1);
                float s2 = fmaf(-2.f, accA[2], nv.z + niA); INS(kA0, kA1, kA2, kA3, s2, idb + 2);
                float s3 = fmaf(-2.f, accA[3], nv.w + niA); INS(kA0, kA1, kA2, kA3, s3, idb + 3);
            }
            {
                float s0 = fmaf(-2.f, accB[0], nv.x + niB); INS(kB0, kB1, kB2, kB3, s0, idb + 0);
                float s1 = fmaf(-2.f, accB[1], nv.y + niB); INS(kB0, kB1, kB2, kB3, s1, idb + 1);
                float s2 = fmaf(-2.f, accB[2], nv.z + niB); INS(kB0, kB1, kB2, kB3, s2, idb + 2);
                float s3 = fmaf(-2.f, accB[3], nv.w + niB); INS(kB0, kB1, kB2, kB3, s3, idb + 3);
            }
            #undef INS
        }
    }

    // Epilogue: merge 4 lq-stripes per row -> top-4 of 16, decode, write cand.
    __syncthreads();
    float* fbuf = (float*)jbuf;                 // 128 rows x 16 keys = 8 KB
    {
        float* pa = fbuf + (w * 32 + lr) * 16 + lq * 4;
        pa[0] = kA0; pa[1] = kA1; pa[2] = kA2; pa[3] = kA3;
        float* pb = fbuf + (w * 32 + 16 + lr) * 16 + lq * 4;
        pb[0] = kB0; pb[1] = kB1; pb[2] = kB2; pb[3] = kB3;
    }
    __syncthreads();
    if (l < 32) {
        int rloc = w * 32 + l;
        const float* pr = fbuf + rloc * 16;
        float m0 = INF, m1 = INF, m2 = INF, m3 = INF;
        #pragma unroll
        for (int q2 = 0; q2 < 16; ++q2) {
            float kf = pr[q2];
            float n0 = fminf(m0, kf);
            float n1 = __builtin_amdgcn_fmed3f(m0, m1, kf);
            float n2 = __builtin_amdgcn_fmed3f(m1, m2, kf);
            float n3 = __builtin_amdgcn_fmed3f(m2, m3, kf);
            m0 = n0; m1 = n1; m2 = n2; m3 = n3;
        }
        ushortx4 cv;
        #define DEC(mf, slot) { unsigned u = __float_as_uint(mf) & 1023u;            \
            cv[slot] = (ushort)(jBase + (((u >> 2) & 63u) << 4) + ((u >> 8) << 2) + (u & 3)); }
        DEC(m0, 0); DEC(m1, 1); DEC(m2, 2); DEC(m3, 3);
        #undef DEC
        int row = b * T_ + i0 + rloc;
        *(ushortx4*)(cand + (size_t)row * 8 + h * 4) = cv;
    }
}

// ---------------------------------------------------------------------------
// Fused refine + gather + conv. Block = (b, 32-i tile), 256 thr, 1024 blocks.
// Phase 1 (R6-validated butterfly refine, now 8 cands): quarter-wave per row,
//   exact fp32 scores, (s,j)-lex top-3 -> jsel in LDS (no global round-trip).
// Phase 2: gather. Phase 3: conv, per-(o,i) fmaf chain identical to R6
//   (bitwise-same output). Coalesced stores.
// ---------------------------------------------------------------------------
__global__ __launch_bounds__(256, 4) void conv_fused_kernel(const float* __restrict__ ws,
                                                            const float* __restrict__ bias,
                                                            float* __restrict__ out) {
    const float*  xT   = ws + XT_OFF;
    const float*  nsq  = ws + NSQ_OFF;
    const float*  Wt   = ws + WT_OFF;
    const ushort* cand = (const ushort*)(ws + CAND_OFF);

    __shared__ float g_s[192 * 32];
    __shared__ int   jsel3[32 * 3];

    int bb  = blockIdx.x >> 6;
    int i0  = (blockIdx.x & 63) * 32;
    int tid = threadIdx.x;
    int w = tid >> 6, l = tid & 63, qw = l >> 4, lr = l & 15;
    int bT = bb * T_;

    // --- Phase 1: exact refine, 2 passes x (4 waves x 4 rows)
    const float INF = __builtin_inff();
    #pragma unroll
    for (int it = 0; it < 2; ++it) {
        int rl  = w * 8 + it * 4 + qw;
        int row = bT + i0 + rl;
        float4 av = *(const float4*)(xT + (size_t)row * 64 + lr * 4);
        int jown = cand[(size_t)row * 8 + (lr & 7)];
        float D0 = INF, D1 = INF, D2 = INF;
        int   I0 = 0x7FFFFFFF, I1 = 0x7FFFFFFF, I2 = 0x7FFFFFFF;
        #pragma unroll
        for (int t = 0; t < 8; ++t) {
            int jt = __shfl(jown, (l & 48) + t, 64);
            float4 bv = *(const float4*)(xT + (size_t)(bT + jt) * 64 + lr * 4);
            float p = fmaf(bv.w, av.w, fmaf(bv.z, av.z, fmaf(bv.y, av.y, bv.x * av.x)));
            p += __shfl_xor(p, 1, 64);
            p += __shfl_xor(p, 2, 64);
            p += __shfl_xor(p, 4, 64);
            p += __shfl_xor(p, 8, 64);
            float s = nsq[bT + jt] - 2.f * p;
            bool lt2 = (s < D2) || (s == D2 && jt < I2);
            bool lt1 = (s < D1) || (s == D1 && jt < I1);
            bool lt0 = (s < D0) || (s == D0 && jt < I0);
            float nD2 = lt1 ? D1 : (lt2 ? s : D2); int nI2 = lt1 ? I1 : (lt2 ? jt : I2);
            float nD1 = lt0 ? D0 : (lt1 ? s : D1); int nI1 = lt0 ? I0 : (lt1 ? jt : I1);
            D2 = nD2; I2 = nI2; D1 = nD1; I1 = nI1;
            D0 = lt0 ? s : D0; I0 = lt0 ? jt : I0;
        }
        if (lr == 0) {
            jsel3[rl * 3 + 0] = I0; jsel3[rl * 3 + 1] = I1; jsel3[rl * 3 + 2] = I2;
        }
    }
    __syncthreads();

    // --- Phase 2: gather 3 neighbor rows per i' -> g_s[m][i']
    if (tid < 96) {
        int k  = tid >> 5;
        int ip = tid & 31;
        int j  = jsel3[ip * 3 + k];
        const float4* src = (const float4*)(xT + (size_t)(bT + j) * 64);
        #pragma unroll
        for (int c4 = 0; c4 < 16; ++c4) {
            float4 v = src[c4];
            int mm = k * 64 + c4 * 4;
            g_s[(mm + 0) * 32 + ip] = v.x;
            g_s[(mm + 1) * 32 + ip] = v.y;
            g_s[(mm + 2) * 32 + ip] = v.z;
            g_s[(mm + 3) * 32 + ip] = v.w;
        }
    }
    __syncthreads();

    // --- Phase 3: conv. thread = 4o x 2i; wv float4 (global, L1 broadcast),
    // gv float2 (LDS). Per-(o,i) accumulation order identical to R6.
    int oq = tid >> 4;        // o = oq*4 .. +3
    int iq = tid & 15;        // i' = iq*2, +1
    float a0x = 0.f, a0y = 0.f, a1x = 0.f, a1y = 0.f;
    float a2x = 0.f, a2y = 0.f, a3x = 0.f, a3y = 0.f;
    #pragma unroll 4
    for (int mm = 0; mm < 192; ++mm) {
        float4 wv = *(const float4*)(Wt + mm * 64 + oq * 4);
        float2 gv = *(const float2*)(g_s + mm * 32 + iq * 2);
        a0x = fmaf(wv.x, gv.x, a0x); a0y = fmaf(wv.x, gv.y, a0y);
        a1x = fmaf(wv.y, gv.x, a1x); a1y = fmaf(wv.y, gv.y, a1y);
        a2x = fmaf(wv.z, gv.x, a2x); a2y = fmaf(wv.z, gv.y, a2y);
        a3x = fmaf(wv.w, gv.x, a3x); a3y = fmaf(wv.w, gv.y, a3y);
    }
    int o0 = oq * 4;
    float b0 = bias[o0], b1 = bias[o0 + 1], b2 = bias[o0 + 2], b3 = bias[o0 + 3];
    float2 r0; r0.x = a0x + b0; r0.y = a0y + b0;
    float2 r1; r1.x = a1x + b1; r1.y = a1y + b1;
    float2 r2; r2.x = a2x + b2; r2.y = a2y + b2;
    float2 r3; r3.x = a3x + b3; r3.y = a3y + b3;
    size_t ob = (size_t)(bb * O_ + o0) * T_ + i0 + iq * 2;
    *(float2*)(out + ob)          = r0;
    *(float2*)(out + ob + T_)     = r1;
    *(float2*)(out + ob + 2 * T_) = r2;
    *(float2*)(out + ob + 3 * T_) = r3;
}

// ---------------------------------------------------------------------------
extern "C" void kernel_launch(void* const* d_in, const int* in_sizes, int n_in,
                              void* d_out, int out_size, void* d_ws, size_t ws_size,
                              hipStream_t stream) {
    const float* x    = (const float*)d_in[0];
    const float* W    = (const float*)d_in[1];
    const float* bias = (const float*)d_in[2];
    float* out = (float*)d_out;
    float* ws  = (float*)d_ws;
    // requires ~17.5 MB workspace (<= 21.2 MB proven)

    prep_kernel<<<B_ * (T_ / 64) + 48, 256, 0, stream>>>(x, W, ws);
    knn_mfma_kernel<<<512, 256, 0, stream>>>(
        (const ushort*)(ws + XS_OFF), ws + NSQ_OFF, (ushort*)(ws + CAND_OFF));
    conv_fused_kernel<<<B_ * 64, 256, 0, stream>>>(ws, bias, out);
}